// Round 13
// baseline (38.613 us; speedup 1.0000x reference)
//
#include <hip/hip_runtime.h>
#include <hip/hip_bf16.h>
#include <math.h>

typedef unsigned short u16;
typedef unsigned int u32;
typedef __attribute__((ext_vector_type(8))) short bf16x8;
typedef __attribute__((ext_vector_type(4))) float f32x4;

#define NB 128
#define ND 1024
#define NO 512
#define EPSV 1e-5f
#define SCALEQK 0.04419417382415922f   // 1/sqrt(512)
#define LOG2E 1.4426950408889634f

static __device__ __forceinline__ float fast_exp2(float v) {
#if __has_builtin(__builtin_amdgcn_exp2f)
  return __builtin_amdgcn_exp2f(v);
#else
  return exp2f(v);
#endif
}
static __device__ __forceinline__ float fast_rcp(float v) {
#if __has_builtin(__builtin_amdgcn_rcpf)
  return __builtin_amdgcn_rcpf(v);
#else
  return 1.f / v;
#endif
}
static __device__ __forceinline__ u16 bf16_rtn(float f) {
  unsigned u = __float_as_uint(f);
  return (u16)((u + 0x7FFFu + ((u >> 16) & 1u)) >> 16);
}
static __device__ __forceinline__ float asinh_fast(float x) {
  const float ax = fabsf(x);
  const float s = sqrtf(fmaf(ax, ax, 1.f));
  return copysignf(__logf(ax + s), x);
}
static __device__ __forceinline__ float tanh_fast(float x) {
  return 1.f - 2.f * fast_rcp(fast_exp2(x * (2.f * LOG2E)) + 1.f);
}
static __device__ __forceinline__ float sig_fast(float x) {
  return fast_rcp(1.f + fast_exp2(-x * LOG2E));
}
static __device__ __forceinline__ float sinh_fast(float x) {
  const float z = fast_exp2(x * LOG2E);
  return 0.5f * (z - fast_rcp(z));
}

// =============== gemmA tile: 128 rows x 64 cols, bf16 single-pass, K-span 256 ===============
// LDS: A [128][128] bf16 swizzled (32 KB) + B [64 col][128 k] (16 KB).
// AMODE 1 = x, 2 = asinh(x). WMODE 0 = plain W0, 1 = tanh(W0)*sigmoid(W1).
template <int AMODE, int WMODE>
static __device__ __forceinline__ void gemmA_tile(
    const float* __restrict__ Xf, const float* __restrict__ W0,
    const float* __restrict__ W1, float* __restrict__ outp,
    int o0, int k0, char* smem) {
  u16* Ash = (u16*)smem;
  u16* Bsh = (u16*)(smem + 32768);
  const int t = threadIdx.x;
  const int lane = t & 63;
  const int wr = (t >> 6) & 3;
  const int wc = t >> 8;
  const f32x4 vz = {0.f, 0.f, 0.f, 0.f};
  f32x4 acc[2][2];
  acc[0][0] = vz; acc[0][1] = vz; acc[1][0] = vz; acc[1][1] = vz;

#pragma unroll
  for (int c = 0; c < 2; ++c) {
    const int kc = k0 + c * 128;
    if (c) __syncthreads();
    // ---- stage A: 4 passes of 32 rows x 128 k; one ds_write_b128 per pass ----
    {
      const int rsub = t >> 4, c8 = (t & 15) * 8;
#pragma unroll
      for (int pass = 0; pass < 4; ++pass) {
        const int row = pass * 32 + rsub;
        const float4 v0 = *(const float4*)(Xf + (size_t)row * ND + kc + c8);
        const float4 v1 = *(const float4*)(Xf + (size_t)row * ND + kc + c8 + 4);
        float e[8] = {v0.x, v0.y, v0.z, v0.w, v1.x, v1.y, v1.z, v1.w};
        if (AMODE == 2) {
#pragma unroll
          for (int i = 0; i < 8; ++i) e[i] = asinh_fast(e[i]);
        }
        u16 h[8];
#pragma unroll
        for (int i = 0; i < 8; ++i) h[i] = bf16_rtn(e[i]);
        const int byte = (row * 256 + c8 * 2) ^ ((row & 7) << 4);
        *(uint4*)((char*)Ash + byte) = make_uint4(
            (u32)h[0] | ((u32)h[1] << 16), (u32)h[2] | ((u32)h[3] << 16),
            (u32)h[4] | ((u32)h[5] << 16), (u32)h[6] | ((u32)h[7] << 16));
      }
    }
    // ---- stage B: [col][k]; reg-transpose, ds_write_b64 per col ----
    {
      const int gkr = t >> 4, og = t & 15;
      const int go = o0 + og * 4;
      float4 w[4];
#pragma unroll
      for (int kk = 0; kk < 4; ++kk) {
        const int gk = kc + gkr * 4 + kk;
        w[kk] = *(const float4*)&W0[(size_t)gk * NO + go];
        if (WMODE) {
          const float4 m = *(const float4*)&W1[(size_t)gk * NO + go];
          w[kk].x = tanh_fast(w[kk].x) * sig_fast(m.x);
          w[kk].y = tanh_fast(w[kk].y) * sig_fast(m.y);
          w[kk].z = tanh_fast(w[kk].z) * sig_fast(m.z);
          w[kk].w = tanh_fast(w[kk].w) * sig_fast(m.w);
        }
      }
      const float* wp0 = (const float*)&w[0];
      const float* wp1 = (const float*)&w[1];
      const float* wp2 = (const float*)&w[2];
      const float* wp3 = (const float*)&w[3];
#pragma unroll
      for (int j = 0; j < 4; ++j) {
        const u16 h0 = bf16_rtn(wp0[j]), h1 = bf16_rtn(wp1[j]);
        const u16 h2 = bf16_rtn(wp2[j]), h3 = bf16_rtn(wp3[j]);
        const int col = og * 4 + j;
        const int byte = (col * 256 + gkr * 8) ^ ((col & 7) << 4);
        *(uint2*)((char*)Bsh + byte) =
            make_uint2((u32)h0 | ((u32)h1 << 16), (u32)h2 | ((u32)h3 << 16));
      }
    }
    __syncthreads();
    // ---- compute: 4 k-steps of 32 ----
#pragma unroll
    for (int ks2 = 0; ks2 < 4; ++ks2) {
      const int kbyte = ks2 * 64 + (lane >> 4) * 16;
      bf16x8 a[2], b[2];
#pragma unroll
      for (int m = 0; m < 2; ++m) {
        const int row = wr * 32 + m * 16 + (lane & 15);
        a[m] = *(const bf16x8*)((const char*)Ash + ((row * 256 + kbyte) ^ ((row & 7) << 4)));
      }
#pragma unroll
      for (int n = 0; n < 2; ++n) {
        const int col = wc * 32 + n * 16 + (lane & 15);
        b[n] = *(const bf16x8*)((const char*)Bsh + ((col * 256 + kbyte) ^ ((col & 7) << 4)));
      }
#pragma unroll
      for (int m = 0; m < 2; ++m)
#pragma unroll
        for (int n = 0; n < 2; ++n)
          acc[m][n] = __builtin_amdgcn_mfma_f32_16x16x32_bf16(a[m], b[n], acc[m][n], 0, 0, 0);
    }
  }
  // ---- epilogue ----
#pragma unroll
  for (int m = 0; m < 2; ++m)
#pragma unroll
    for (int n = 0; n < 2; ++n) {
      const int col = o0 + wc * 32 + n * 16 + (lane & 15);
#pragma unroll
      for (int r = 0; r < 4; ++r) {
        const int row = wr * 32 + m * 16 + (lane >> 4) * 4 + r;
        outp[(size_t)row * NO + col] = acc[m][n][r];
      }
    }
}

// =============== K1: attn (0..127) | gemmA (128..255) | UVW (256..263) ===============
__global__ __launch_bounds__(512) void k1_fused(
    const float* __restrict__ x, const float* __restrict__ gt,
    const float* __restrict__ wt, const float* __restrict__ mt,
    const float* __restrict__ k1w, const float* __restrict__ embk,
    const float* __restrict__ embb, const float* __restrict__ ekd,
    const float* __restrict__ k3w, const float* __restrict__ ng,
    const float* __restrict__ nbv, float* __restrict__ Tfull,
    float* __restrict__ pA, float* __restrict__ U, float* __restrict__ V,
    float* __restrict__ Wc) {
  __shared__ __align__(16) char smem[49152];
  const int bid = blockIdx.x;
  const int t = threadIdx.x;
  const int wv = t >> 6;

  if (bid < NB) {
    // ---- attention: T_b via tilted moments + order-5 Taylor ----
    float* xsh = (float*)smem;
    float(*red)[8] = (float(*)[8])(smem + 4096);
    float* bc = (float*)(smem + 4096 + 7 * 8 * 4);
    *(float2*)&xsh[t * 2] = *(const float2*)&x[bid * ND + t * 2];
    float s1, s3;
    {
      const float kk = embk[NO + t];
      s1 = embk[t] * kk;
      s3 = kk * embb[t];
    }
#pragma unroll
    for (int off = 32; off; off >>= 1) {
      s1 += __shfl_xor(s1, off);
      s3 += __shfl_xor(s3, off);
    }
    if ((t & 63) == 0) { red[0][wv] = s1; red[1][wv] = s3; }
    __syncthreads();
    if (t < 2) {
      float v = 0.f;
#pragma unroll
      for (int i = 0; i < 8; ++i) v += red[t][i];
      bc[t] = v;
    }
    __syncthreads();
    const float S1 = bc[0], S3 = bc[1];
    const float aL2 = SCALEQK * LOG2E * S3;
    const float dS1 = SCALEQK * S1;
    float mm[7];
#pragma unroll
    for (int k = 0; k < 7; ++k) mm[k] = 0.f;
#pragma unroll
    for (int j = 0; j < 2; ++j) {
      const float xe = xsh[t * 2 + j];
      float p = fast_exp2(aL2 * xe);
      mm[0] += p;
#pragma unroll
      for (int k = 1; k < 7; ++k) { p *= xe; mm[k] += p; }
    }
#pragma unroll
    for (int off = 32; off; off >>= 1)
#pragma unroll
      for (int k = 0; k < 7; ++k) mm[k] += __shfl_xor(mm[k], off);
    if ((t & 63) == 0)
#pragma unroll
      for (int k = 0; k < 7; ++k) red[k][wv] = mm[k];
    __syncthreads();
    if (t < 7) {
      float v = 0.f;
#pragma unroll
      for (int i = 0; i < 8; ++i) v += red[t][i];
      bc[2 + t] = v;
    }
    __syncthreads();
    const float invf[6] = {1.f, 1.f, 0.5f, 1.6666667e-1f, 4.1666668e-2f, 8.3333333e-3f};
    float cn[6], cd[6];
#pragma unroll
    for (int k = 0; k < 6; ++k) {
      cn[k] = bc[3 + k] * invf[k];
      cd[k] = bc[2 + k] * invf[k];
    }
    float Ta = 0.f;
#pragma unroll
    for (int j = 0; j < 2; ++j) {
      const int d = t * 2 + j;
      const float del = dS1 * xsh[d];
      float num = cn[5], den = cd[5];
#pragma unroll
      for (int k = 4; k >= 0; --k) {
        num = fmaf(num, del, cn[k]);
        den = fmaf(den, del, cd[k]);
      }
      Ta = fmaf(ekd[d], num / den, Ta);
    }
#pragma unroll
    for (int off = 32; off; off >>= 1) Ta += __shfl_xor(Ta, off);
    __syncthreads();
    if ((t & 63) == 0) red[0][wv] = Ta;
    __syncthreads();
    if (t == 0) {
      float v = 0.f;
#pragma unroll
      for (int i = 0; i < 8; ++i) v += red[0][i];
      Tfull[bid] = v;
    }
    return;
  }
  if (bid < 256) {
    // ---- gemmA: g4 x ks4 x ot8 ----
    const int b2 = bid - NB;
    const int g = b2 >> 5, ks = (b2 >> 3) & 3, ot = b2 & 7;
    float* outp = pA + (size_t)(g * 4 + ks) * (NB * NO);
    if (g == 0)
      gemmA_tile<1, 0>(x, k1w, k1w, outp, ot * 64, ks * 256, smem);
    else if (g == 1)
      gemmA_tile<1, 0>(x, gt, gt, outp, ot * 64, ks * 256, smem);
    else if (g == 2)
      gemmA_tile<1, 1>(x, wt, mt, outp, ot * 64, ks * 256, smem);
    else
      gemmA_tile<2, 1>(x, wt, mt, outp, ot * 64, ks * 256, smem);
    return;
  }
  // ---- UVW: U=u@K33, V=v@K33, Wc=nb@K33; u=(vk-mvk)*ng, v=(vb-mvb)*ng ----
  {
    float(*lds)[64][3] = (float(*)[64][3])smem;
    __shared__ float mred[2][8];
    __shared__ float mbc[2];
    float svk = embk[2 * NO + t], svb = embb[2 * NO + t];
#pragma unroll
    for (int off = 32; off; off >>= 1) {
      svk += __shfl_xor(svk, off);
      svb += __shfl_xor(svb, off);
    }
    if ((t & 63) == 0) { mred[0][wv] = svk; mred[1][wv] = svb; }
    __syncthreads();
    if (t < 2) {
      float s = 0.f;
#pragma unroll
      for (int i = 0; i < 8; ++i) s += mred[t][i];
      mbc[t] = s * (1.f / (float)NO);
    }
    __syncthreads();
    const float mvk = mbc[0], mvb = mbc[1];
    const int jbase = (bid - 256) * 64;
    const int j = jbase + (t & 63);
    const int oc = t >> 6;
    float au = 0.f, av = 0.f, aw = 0.f;
#pragma unroll 4
    for (int oo = 0; oo < 64; ++oo) {
      const int o = oc * 64 + oo;
      const float kj = k3w[(size_t)(2 * NO + o) * NO + j];
      const float g = ng[o];
      au = fmaf((embk[2 * NO + o] - mvk) * g, kj, au);
      av = fmaf((embb[2 * NO + o] - mvb) * g, kj, av);
      aw = fmaf(nbv[o], kj, aw);
    }
    lds[oc][t & 63][0] = au;
    lds[oc][t & 63][1] = av;
    lds[oc][t & 63][2] = aw;
    __syncthreads();
    if (t < 64) {
      float su = 0.f, sv = 0.f, sw = 0.f;
#pragma unroll
      for (int cch = 0; cch < 8; ++cch) {
        su += lds[cch][t][0];
        sv += lds[cch][t][1];
        sw += lds[cch][t][2];
      }
      U[jbase + t] = su;
      V[jbase + t] = sv;
      Wc[jbase + t] = sw;
    }
  }
}

// =============== K2': fused combineA + gemmB; 128 blocks (2rh x 8ks x 8ot), 64x64, K=128 ===============
// A-tile synthesized from pA (c1 or c3 inline); atomicAdd into zeroed out; ks==0 adds
// b3 + rank-2 c4 (aS*U + cS*V + Wc).
__global__ __launch_bounds__(512) void k2_gemmB_fused(
    const float* __restrict__ pA, const float* __restrict__ b1v,
    const float* __restrict__ k3w, const float* __restrict__ embk,
    const float* __restrict__ embb, const float* __restrict__ ekd,
    const float* __restrict__ Tfull, const float* __restrict__ U,
    const float* __restrict__ V, const float* __restrict__ Wc,
    const float* __restrict__ b3, float* __restrict__ out) {
  __shared__ __align__(16) char smem[32768];
  u16* Ash = (u16*)smem;                 // [64][128] bf16 swizzled, 16 KB
  u16* Bsh = (u16*)(smem + 16384);       // [64 col][128 k], 16 KB
  __shared__ float red6[6][8];
  __shared__ float bc6[6];
  __shared__ float aSl[64];
  __shared__ float cSl[64];
  const int t = threadIdx.x;
  const int wv = t >> 6;
  const int lane = t & 63;
  const int wr = wv & 3, wc = wv >> 2;
  const int rh = blockIdx.x >> 6, ks = (blockIdx.x >> 3) & 7, ot = blockIdx.x & 7;
  const int r0 = rh * 64, k0 = ks * 128, o0 = ot * 64;

  // ---- prologue (ks==0 blocks only): layernorm scalars for rank-2 c4 ----
  if (ks == 0) {
    const float vk = embk[2 * NO + t], vb = embb[2 * NO + t];
    float svk = vk, svb = vb, svk2 = vk * vk, svkvb = vk * vb, svb2 = vb * vb;
    float se = ekd[t] + ekd[t + 512];
#pragma unroll
    for (int off = 32; off; off >>= 1) {
      svk += __shfl_xor(svk, off); svb += __shfl_xor(svb, off);
      svk2 += __shfl_xor(svk2, off); svkvb += __shfl_xor(svkvb, off);
      svb2 += __shfl_xor(svb2, off); se += __shfl_xor(se, off);
    }
    if ((t & 63) == 0) {
      red6[0][wv] = svk; red6[1][wv] = svb; red6[2][wv] = svk2;
      red6[3][wv] = svkvb; red6[4][wv] = svb2; red6[5][wv] = se;
    }
    __syncthreads();
    if (t < 6) {
      float s = 0.f;
#pragma unroll
      for (int i = 0; i < 8; ++i) s += red6[t][i];
      bc6[t] = s;
    }
    __syncthreads();
    const float inv_o = 1.f / (float)NO;
    const float mvk = bc6[0] * inv_o, mvb = bc6[1] * inv_o;
    const float Mvk2 = bc6[2] * inv_o - mvk * mvk;
    const float Mvkvb = bc6[3] * inv_o - mvk * mvb;
    const float Mvb2 = bc6[4] * inv_o - mvb * mvb;
    const float E = bc6[5];
    if (t < 64) {
      const float T = Tfull[r0 + t];
      const float var = T * T * Mvk2 + 2.f * T * E * Mvkvb + E * E * Mvb2;
      const float rs = rsqrtf(var + EPSV);
      aSl[t] = T * rs;
      cSl[t] = E * rs;
    }
    __syncthreads();
  }

  // ---- stage A: synthesize feat rows r0..r0+63, cols k0..k0+127 from pA ----
  {
    const int row = t >> 3;           // 0..63
    const int jj = (t & 7) * 16;      // 0..112
    const int j = k0 + jj;            // global feat col
    const size_t rowoff = (size_t)(r0 + row) * NO;
    float e[16];
    if (ks < 4) {
      // c1 = sum slots 0..3 + b1
#pragma unroll
      for (int q = 0; q < 4; ++q) {
        float4 d = *(const float4*)&pA[rowoff + j + q * 4];
#pragma unroll
        for (int s = 1; s < 4; ++s) {
          const float4 v = *(const float4*)&pA[(size_t)s * (NB * NO) + rowoff + j + q * 4];
          d.x += v.x; d.y += v.y; d.z += v.z; d.w += v.w;
        }
        const float4 bb = *(const float4*)&b1v[j + q * 4];
        e[q * 4 + 0] = d.x + bb.x; e[q * 4 + 1] = d.y + bb.y;
        e[q * 4 + 2] = d.z + bb.z; e[q * 4 + 3] = d.w + bb.w;
      }
    } else {
      const int o = j - NO;
#pragma unroll
      for (int q = 0; q < 4; ++q) {
        float4 d2 = {0, 0, 0, 0}, d3 = {0, 0, 0, 0}, d4 = {0, 0, 0, 0};
#pragma unroll
        for (int s = 0; s < 4; ++s) {
          const size_t base = rowoff + o + q * 4;
          const float4 v2 = *(const float4*)&pA[(size_t)(4 + s) * (NB * NO) + base];
          const float4 v3 = *(const float4*)&pA[(size_t)(8 + s) * (NB * NO) + base];
          const float4 v4 = *(const float4*)&pA[(size_t)(12 + s) * (NB * NO) + base];
          d2.x += v2.x; d2.y += v2.y; d2.z += v2.z; d2.w += v2.w;
          d3.x += v3.x; d3.y += v3.y; d3.z += v3.z; d3.w += v3.w;
          d4.x += v4.x; d4.y += v4.y; d4.z += v4.z; d4.w += v4.w;
        }
        const float g0 = sig_fast(d2.x), g1 = sig_fast(d2.y);
        const float g2 = sig_fast(d2.z), g3 = sig_fast(d2.w);
        const float s0 = sinh_fast(d4.x), s1 = sinh_fast(d4.y);
        const float s2 = sinh_fast(d4.z), s3 = sinh_fast(d4.w);
        e[q * 4 + 0] = fmaf(g0, d3.x - s0, s0);
        e[q * 4 + 1] = fmaf(g1, d3.y - s1, s1);
        e[q * 4 + 2] = fmaf(g2, d3.z - s2, s2);
        e[q * 4 + 3] = fmaf(g3, d3.w - s3, s3);
      }
    }
    u16 h[16];
#pragma unroll
    for (int i = 0; i < 16; ++i) h[i] = bf16_rtn(e[i]);
    const int swz = (row & 7) << 4;
    const int byte0 = (row * 256 + jj * 2) ^ swz;
    const int byte1 = (row * 256 + jj * 2 + 16) ^ swz;
    *(uint4*)((char*)Ash + byte0) = make_uint4(
        (u32)h[0] | ((u32)h[1] << 16), (u32)h[2] | ((u32)h[3] << 16),
        (u32)h[4] | ((u32)h[5] << 16), (u32)h[6] | ((u32)h[7] << 16));
    *(uint4*)((char*)Ash + byte1) = make_uint4(
        (u32)h[8] | ((u32)h[9] << 16), (u32)h[10] | ((u32)h[11] << 16),
        (u32)h[12] | ((u32)h[13] << 16), (u32)h[14] | ((u32)h[15] << 16));
  }
  // ---- stage B: k3 rows k0..k0+127, cols o0..o0+63; reg-transpose, ds_write_b64 ----
  {
    const int gkr = t >> 4, og = t & 15;
    const int go = o0 + og * 4;
    float4 w[4];
#pragma unroll
    for (int kk = 0; kk < 4; ++kk)
      w[kk] = *(const float4*)&k3w[(size_t)(k0 + gkr * 4 + kk) * NO + go];
    const float* wp0 = (const float*)&w[0];
    const float* wp1 = (const float*)&w[1];
    const float* wp2 = (const float*)&w[2];
    const float* wp3 = (const float*)&w[3];
#pragma unroll
    for (int j = 0; j < 4; ++j) {
      const u16 h0 = bf16_rtn(wp0[j]), h1 = bf16_rtn(wp1[j]);
      const u16 h2 = bf16_rtn(wp2[j]), h3 = bf16_rtn(wp3[j]);
      const int col = og * 4 + j;
      const int byte = (col * 256 + gkr * 8) ^ ((col & 7) << 4);
      *(uint2*)((char*)Bsh + byte) =
          make_uint2((u32)h0 | ((u32)h1 << 16), (u32)h2 | ((u32)h3 << 16));
    }
  }
  __syncthreads();
  // ---- compute: 4 k-steps of 32; 8 waves (wr4 x wc2), acc[2] ----
  const f32x4 vz = {0.f, 0.f, 0.f, 0.f};
  f32x4 acc[2];
  acc[0] = vz; acc[1] = vz;
#pragma unroll
  for (int ks2 = 0; ks2 < 4; ++ks2) {
    const int kbyte = ks2 * 64 + (lane >> 4) * 16;
    const int row = wr * 16 + (lane & 15);
    const bf16x8 a = *(const bf16x8*)((const char*)Ash + ((row * 256 + kbyte) ^ ((row & 7) << 4)));
#pragma unroll
    for (int n = 0; n < 2; ++n) {
      const int col = wc * 32 + n * 16 + (lane & 15);
      const bf16x8 b = *(const bf16x8*)((const char*)Bsh + ((col * 256 + kbyte) ^ ((col & 7) << 4)));
      acc[n] = __builtin_amdgcn_mfma_f32_16x16x32_bf16(a, b, acc[n], 0, 0, 0);
    }
  }
  // ---- epilogue: atomicAdd into zeroed out; ks==0 adds bias + rank-2 c4 ----
#pragma unroll
  for (int n = 0; n < 2; ++n) {
    const int col = o0 + wc * 32 + n * 16 + (lane & 15);
    float base = 0.f, uc = 0.f, vc = 0.f;
    if (ks == 0) { base = b3[col] + Wc[col]; uc = U[col]; vc = V[col]; }
#pragma unroll
    for (int r = 0; r < 4; ++r) {
      const int rl = wr * 16 + (lane >> 4) * 4 + r;
      float add = acc[n][r];
      if (ks == 0) add += fmaf(aSl[rl], uc, fmaf(cSl[rl], vc, base));
      atomicAdd(&out[(size_t)(r0 + rl) * NO + col], add);
    }
  }
}

extern "C" void kernel_launch(void* const* d_in, const int* in_sizes, int n_in,
                              void* d_out, int out_size, void* d_ws, size_t ws_size,
                              hipStream_t stream) {
  const float* x    = (const float*)d_in[0];
  const float* gt   = (const float*)d_in[1];
  const float* wt   = (const float*)d_in[2];
  const float* mt   = (const float*)d_in[3];
  const float* k1   = (const float*)d_in[4];
  const float* b1   = (const float*)d_in[5];
  const float* k3   = (const float*)d_in[6];
  const float* b3   = (const float*)d_in[7];
  const float* embk = (const float*)d_in[8];
  const float* embb = (const float*)d_in[9];
  const float* ekd  = (const float*)d_in[10];
  const float* ng   = (const float*)d_in[11];
  const float* nb   = (const float*)d_in[12];

  char* wsb = (char*)d_ws;
  float* Tfull = (float*)wsb;                        // 512 B
  float* U  = (float*)(wsb + 4096);                  // 2 KB each
  float* V  = (float*)(wsb + 8192);
  float* Wc = (float*)(wsb + 12288);
  float* pA = (float*)(wsb + (1u << 20));            // 16*128*512*4 = 4 MB
  float* out = (float*)d_out;

  hipMemsetAsync(out, 0, (size_t)out_size * sizeof(float), stream);
  hipLaunchKernelGGL(k1_fused, dim3(264), dim3(512), 0, stream,
                     x, gt, wt, mt, k1, embk, embb, ekd, k3, ng, nb,
                     Tfull, pA, U, V, Wc);
  hipLaunchKernelGGL(k2_gemmB_fused, dim3(128), dim3(512), 0, stream,
                     pA, b1, k3, embk, embb, ekd, Tfull, U, V, Wc, b3, out);
}

// Round 14
// 24.611 us; speedup vs baseline: 1.5689x; 1.5689x over previous
//
#include <hip/hip_runtime.h>
#include <hip/hip_bf16.h>
#include <math.h>

typedef unsigned short u16;
typedef unsigned int u32;
typedef __attribute__((ext_vector_type(8))) short bf16x8;
typedef __attribute__((ext_vector_type(4))) float f32x4;

#define NB 128
#define ND 1024
#define NO 512
#define EPSV 1e-5f
#define SCALEQK 0.04419417382415922f   // 1/sqrt(512)
#define LOG2E 1.4426950408889634f

static __device__ __forceinline__ float fast_exp2(float v) {
#if __has_builtin(__builtin_amdgcn_exp2f)
  return __builtin_amdgcn_exp2f(v);
#else
  return exp2f(v);
#endif
}
static __device__ __forceinline__ float fast_rcp(float v) {
#if __has_builtin(__builtin_amdgcn_rcpf)
  return __builtin_amdgcn_rcpf(v);
#else
  return 1.f / v;
#endif
}
static __device__ __forceinline__ u16 bf16_rtn(float f) {
  unsigned u = __float_as_uint(f);
  return (u16)((u + 0x7FFFu + ((u >> 16) & 1u)) >> 16);
}
static __device__ __forceinline__ float asinh_fast(float x) {
  const float ax = fabsf(x);
  const float s = sqrtf(fmaf(ax, ax, 1.f));
  return copysignf(__logf(ax + s), x);
}
static __device__ __forceinline__ float tanh_fast(float x) {
  return 1.f - 2.f * fast_rcp(fast_exp2(x * (2.f * LOG2E)) + 1.f);
}
static __device__ __forceinline__ float sig_fast(float x) {
  return fast_rcp(1.f + fast_exp2(-x * LOG2E));
}
static __device__ __forceinline__ float sinh_fast(float x) {
  const float z = fast_exp2(x * LOG2E);
  return 0.5f * (z - fast_rcp(z));
}

// =============== gemmA tile: 128 rows x 64 cols, K-span 128, ONE stage+compute phase ===============
// All global loads issued into registers before any cvt/LDS work (latency batching).
// AMODE 1 = x, 2 = asinh(x). WMODE 0 = plain W0, 1 = tanh(W0)*sigmoid(W1).
template <int AMODE, int WMODE>
static __device__ __forceinline__ void gemmA_tile(
    const float* __restrict__ Xf, const float* __restrict__ W0,
    const float* __restrict__ W1, float* __restrict__ outp,
    int o0, int k0, char* smem) {
  u16* Ash = (u16*)smem;                 // [128][128] bf16 swizzled, 32 KB
  u16* Bsh = (u16*)(smem + 32768);       // [64 col][128 k], 16 KB
  const int t = threadIdx.x;
  const int lane = t & 63;
  const int wr = (t >> 6) & 3;
  const int wc = t >> 8;

  // ---- batched global loads: A (8 x float4) then B (4..8 x float4) ----
  const int rsub = t >> 4, c8 = (t & 15) * 8;
  float4 va[4], vb[4];
#pragma unroll
  for (int pass = 0; pass < 4; ++pass) {
    const size_t rowoff = (size_t)(pass * 32 + rsub) * ND + k0 + c8;
    va[pass] = *(const float4*)(Xf + rowoff);
    vb[pass] = *(const float4*)(Xf + rowoff + 4);
  }
  const int gkr = t >> 4, og = t & 15;
  const int go = o0 + og * 4;
  float4 w[4], mw[4];
#pragma unroll
  for (int kk = 0; kk < 4; ++kk) {
    w[kk] = *(const float4*)&W0[(size_t)(k0 + gkr * 4 + kk) * NO + go];
    if (WMODE) mw[kk] = *(const float4*)&W1[(size_t)(k0 + gkr * 4 + kk) * NO + go];
  }

  // ---- cvt + LDS write A ----
#pragma unroll
  for (int pass = 0; pass < 4; ++pass) {
    const int row = pass * 32 + rsub;
    float e[8] = {va[pass].x, va[pass].y, va[pass].z, va[pass].w,
                  vb[pass].x, vb[pass].y, vb[pass].z, vb[pass].w};
    if (AMODE == 2) {
#pragma unroll
      for (int i = 0; i < 8; ++i) e[i] = asinh_fast(e[i]);
    }
    u16 h[8];
#pragma unroll
    for (int i = 0; i < 8; ++i) h[i] = bf16_rtn(e[i]);
    const int byte = (row * 256 + c8 * 2) ^ ((row & 7) << 4);
    *(uint4*)((char*)Ash + byte) = make_uint4(
        (u32)h[0] | ((u32)h[1] << 16), (u32)h[2] | ((u32)h[3] << 16),
        (u32)h[4] | ((u32)h[5] << 16), (u32)h[6] | ((u32)h[7] << 16));
  }
  // ---- cvt + LDS write B (register transpose, ds_write_b64 per col) ----
  {
    if (WMODE) {
#pragma unroll
      for (int kk = 0; kk < 4; ++kk) {
        w[kk].x = tanh_fast(w[kk].x) * sig_fast(mw[kk].x);
        w[kk].y = tanh_fast(w[kk].y) * sig_fast(mw[kk].y);
        w[kk].z = tanh_fast(w[kk].z) * sig_fast(mw[kk].z);
        w[kk].w = tanh_fast(w[kk].w) * sig_fast(mw[kk].w);
      }
    }
    const float* wp0 = (const float*)&w[0];
    const float* wp1 = (const float*)&w[1];
    const float* wp2 = (const float*)&w[2];
    const float* wp3 = (const float*)&w[3];
#pragma unroll
    for (int j = 0; j < 4; ++j) {
      const u16 h0 = bf16_rtn(wp0[j]), h1 = bf16_rtn(wp1[j]);
      const u16 h2 = bf16_rtn(wp2[j]), h3 = bf16_rtn(wp3[j]);
      const int col = og * 4 + j;
      const int byte = (col * 256 + gkr * 8) ^ ((col & 7) << 4);
      *(uint2*)((char*)Bsh + byte) =
          make_uint2((u32)h0 | ((u32)h1 << 16), (u32)h2 | ((u32)h3 << 16));
    }
  }
  __syncthreads();
  // ---- compute: 4 k-steps of 32 ----
  const f32x4 vz = {0.f, 0.f, 0.f, 0.f};
  f32x4 acc[2][2];
  acc[0][0] = vz; acc[0][1] = vz; acc[1][0] = vz; acc[1][1] = vz;
#pragma unroll
  for (int ks2 = 0; ks2 < 4; ++ks2) {
    const int kbyte = ks2 * 64 + (lane >> 4) * 16;
    bf16x8 a[2], b[2];
#pragma unroll
    for (int m = 0; m < 2; ++m) {
      const int row = wr * 32 + m * 16 + (lane & 15);
      a[m] = *(const bf16x8*)((const char*)Ash + ((row * 256 + kbyte) ^ ((row & 7) << 4)));
    }
#pragma unroll
    for (int n = 0; n < 2; ++n) {
      const int col = wc * 32 + n * 16 + (lane & 15);
      b[n] = *(const bf16x8*)((const char*)Bsh + ((col * 256 + kbyte) ^ ((col & 7) << 4)));
    }
#pragma unroll
    for (int m = 0; m < 2; ++m)
#pragma unroll
      for (int n = 0; n < 2; ++n)
        acc[m][n] = __builtin_amdgcn_mfma_f32_16x16x32_bf16(a[m], b[n], acc[m][n], 0, 0, 0);
  }
  // ---- epilogue ----
#pragma unroll
  for (int m = 0; m < 2; ++m)
#pragma unroll
    for (int n = 0; n < 2; ++n) {
      const int col = o0 + wc * 32 + n * 16 + (lane & 15);
#pragma unroll
      for (int r = 0; r < 4; ++r) {
        const int row = wr * 32 + m * 16 + (lane >> 4) * 4 + r;
        outp[(size_t)row * NO + col] = acc[m][n][r];
      }
    }
}

// =============== K1: attn (0..127) | gemmA (128..383: g4 x ks8 x ot8) | UVW (384..391) ===============
__global__ __launch_bounds__(512) void k1_fused(
    const float* __restrict__ x, const float* __restrict__ gt,
    const float* __restrict__ wt, const float* __restrict__ mt,
    const float* __restrict__ k1w, const float* __restrict__ embk,
    const float* __restrict__ embb, const float* __restrict__ ekd,
    const float* __restrict__ k3w, const float* __restrict__ ng,
    const float* __restrict__ nbv, float* __restrict__ Tfull,
    float* __restrict__ pA, float* __restrict__ U, float* __restrict__ V,
    float* __restrict__ Wc) {
  __shared__ __align__(16) char smem[49152];
  const int bid = blockIdx.x;
  const int t = threadIdx.x;
  const int wv = t >> 6;

  if (bid < NB) {
    // ---- attention: T_b via tilted moments + order-5 Taylor ----
    float* xsh = (float*)smem;
    float(*red)[8] = (float(*)[8])(smem + 4096);
    float* bc = (float*)(smem + 4096 + 7 * 8 * 4);
    *(float2*)&xsh[t * 2] = *(const float2*)&x[bid * ND + t * 2];
    float s1, s3;
    {
      const float kk = embk[NO + t];
      s1 = embk[t] * kk;
      s3 = kk * embb[t];
    }
#pragma unroll
    for (int off = 32; off; off >>= 1) {
      s1 += __shfl_xor(s1, off);
      s3 += __shfl_xor(s3, off);
    }
    if ((t & 63) == 0) { red[0][wv] = s1; red[1][wv] = s3; }
    __syncthreads();
    if (t < 2) {
      float v = 0.f;
#pragma unroll
      for (int i = 0; i < 8; ++i) v += red[t][i];
      bc[t] = v;
    }
    __syncthreads();
    const float S1 = bc[0], S3 = bc[1];
    const float aL2 = SCALEQK * LOG2E * S3;
    const float dS1 = SCALEQK * S1;
    float mm[7];
#pragma unroll
    for (int k = 0; k < 7; ++k) mm[k] = 0.f;
#pragma unroll
    for (int j = 0; j < 2; ++j) {
      const float xe = xsh[t * 2 + j];
      float p = fast_exp2(aL2 * xe);
      mm[0] += p;
#pragma unroll
      for (int k = 1; k < 7; ++k) { p *= xe; mm[k] += p; }
    }
#pragma unroll
    for (int off = 32; off; off >>= 1)
#pragma unroll
      for (int k = 0; k < 7; ++k) mm[k] += __shfl_xor(mm[k], off);
    if ((t & 63) == 0)
#pragma unroll
      for (int k = 0; k < 7; ++k) red[k][wv] = mm[k];
    __syncthreads();
    if (t < 7) {
      float v = 0.f;
#pragma unroll
      for (int i = 0; i < 8; ++i) v += red[t][i];
      bc[2 + t] = v;
    }
    __syncthreads();
    const float invf[6] = {1.f, 1.f, 0.5f, 1.6666667e-1f, 4.1666668e-2f, 8.3333333e-3f};
    float cn[6], cd[6];
#pragma unroll
    for (int k = 0; k < 6; ++k) {
      cn[k] = bc[3 + k] * invf[k];
      cd[k] = bc[2 + k] * invf[k];
    }
    float Ta = 0.f;
#pragma unroll
    for (int j = 0; j < 2; ++j) {
      const int d = t * 2 + j;
      const float del = dS1 * xsh[d];
      float num = cn[5], den = cd[5];
#pragma unroll
      for (int k = 4; k >= 0; --k) {
        num = fmaf(num, del, cn[k]);
        den = fmaf(den, del, cd[k]);
      }
      Ta = fmaf(ekd[d], num / den, Ta);
    }
#pragma unroll
    for (int off = 32; off; off >>= 1) Ta += __shfl_xor(Ta, off);
    __syncthreads();
    if ((t & 63) == 0) red[0][wv] = Ta;
    __syncthreads();
    if (t == 0) {
      float v = 0.f;
#pragma unroll
      for (int i = 0; i < 8; ++i) v += red[0][i];
      Tfull[bid] = v;
    }
    return;
  }
  if (bid < 384) {
    // ---- gemmA: g4 x ks8 x ot8, single K-chunk of 128 ----
    const int b2 = bid - NB;
    const int g = b2 >> 6, ks = (b2 >> 3) & 7, ot = b2 & 7;
    float* outp = pA + (size_t)(g * 8 + ks) * (NB * NO);
    if (g == 0)
      gemmA_tile<1, 0>(x, k1w, k1w, outp, ot * 64, ks * 128, smem);
    else if (g == 1)
      gemmA_tile<1, 0>(x, gt, gt, outp, ot * 64, ks * 128, smem);
    else if (g == 2)
      gemmA_tile<1, 1>(x, wt, mt, outp, ot * 64, ks * 128, smem);
    else
      gemmA_tile<2, 1>(x, wt, mt, outp, ot * 64, ks * 128, smem);
    return;
  }
  // ---- UVW: U=u@K33, V=v@K33, Wc=nb@K33; u=(vk-mvk)*ng, v=(vb-mvb)*ng ----
  {
    float(*lds)[64][3] = (float(*)[64][3])smem;
    __shared__ float mred[2][8];
    __shared__ float mbc[2];
    float svk = embk[2 * NO + t], svb = embb[2 * NO + t];
#pragma unroll
    for (int off = 32; off; off >>= 1) {
      svk += __shfl_xor(svk, off);
      svb += __shfl_xor(svb, off);
    }
    if ((t & 63) == 0) { mred[0][wv] = svk; mred[1][wv] = svb; }
    __syncthreads();
    if (t < 2) {
      float s = 0.f;
#pragma unroll
      for (int i = 0; i < 8; ++i) s += mred[t][i];
      mbc[t] = s * (1.f / (float)NO);
    }
    __syncthreads();
    const float mvk = mbc[0], mvb = mbc[1];
    const int jbase = (bid - 384) * 64;
    const int j = jbase + (t & 63);
    const int oc = t >> 6;
    float au = 0.f, av = 0.f, aw = 0.f;
#pragma unroll 4
    for (int oo = 0; oo < 64; ++oo) {
      const int o = oc * 64 + oo;
      const float kj = k3w[(size_t)(2 * NO + o) * NO + j];
      const float g = ng[o];
      au = fmaf((embk[2 * NO + o] - mvk) * g, kj, au);
      av = fmaf((embb[2 * NO + o] - mvb) * g, kj, av);
      aw = fmaf(nbv[o], kj, aw);
    }
    lds[oc][t & 63][0] = au;
    lds[oc][t & 63][1] = av;
    lds[oc][t & 63][2] = aw;
    __syncthreads();
    if (t < 64) {
      float su = 0.f, sv = 0.f, sw = 0.f;
#pragma unroll
      for (int cch = 0; cch < 8; ++cch) {
        su += lds[cch][t][0];
        sv += lds[cch][t][1];
        sw += lds[cch][t][2];
      }
      U[jbase + t] = su;
      V[jbase + t] = sv;
      Wc[jbase + t] = sw;
    }
  }
}

// =============== K2: combineA -> featB (bf16) + out init (b3 + rank-2 c4) ===============
__global__ __launch_bounds__(512) void k2_combineA(
    const float* __restrict__ pA, const float* __restrict__ b1,
    const float* __restrict__ embk, const float* __restrict__ embb,
    const float* __restrict__ ekd, const float* __restrict__ Tfull,
    const float* __restrict__ U, const float* __restrict__ V,
    const float* __restrict__ Wc, const float* __restrict__ b3,
    u16* __restrict__ featB, float* __restrict__ out) {
  __shared__ float red6[6][8];
  __shared__ float bc6[6];
  const int b = blockIdx.x, t = threadIdx.x;
  const int wv = t >> 6;
  {
    const float vk = embk[2 * NO + t], vb = embb[2 * NO + t];
    float svk = vk, svb = vb, svk2 = vk * vk, svkvb = vk * vb, svb2 = vb * vb;
    float se = ekd[t] + ekd[t + 512];
#pragma unroll
    for (int off = 32; off; off >>= 1) {
      svk += __shfl_xor(svk, off); svb += __shfl_xor(svb, off);
      svk2 += __shfl_xor(svk2, off); svkvb += __shfl_xor(svkvb, off);
      svb2 += __shfl_xor(svb2, off); se += __shfl_xor(se, off);
    }
    if ((t & 63) == 0) {
      red6[0][wv] = svk; red6[1][wv] = svb; red6[2][wv] = svk2;
      red6[3][wv] = svkvb; red6[4][wv] = svb2; red6[5][wv] = se;
    }
    __syncthreads();
    if (t < 6) {
      float s = 0.f;
#pragma unroll
      for (int i = 0; i < 8; ++i) s += red6[t][i];
      bc6[t] = s;
    }
    __syncthreads();
  }
  const float inv_o = 1.f / (float)NO;
  const float mvk = bc6[0] * inv_o, mvb = bc6[1] * inv_o;
  const float Mvk2 = bc6[2] * inv_o - mvk * mvk;
  const float Mvkvb = bc6[3] * inv_o - mvk * mvb;
  const float Mvb2 = bc6[4] * inv_o - mvb * mvb;
  const float E = bc6[5];
  const float T = Tfull[b];
  const float var = T * T * Mvk2 + 2.f * T * E * Mvkvb + E * E * Mvb2;
  const float rs = rsqrtf(var + EPSV);
  const float aS = T * rs, cS = E * rs;

  const size_t off = (size_t)b * NO + t;
  // batched loads: 32 slot values
  float v1[8], v2[8], v3[8], v4[8];
#pragma unroll
  for (int s = 0; s < 8; ++s) {
    v1[s] = pA[(size_t)(0 * 8 + s) * (NB * NO) + off];
    v2[s] = pA[(size_t)(1 * 8 + s) * (NB * NO) + off];
    v3[s] = pA[(size_t)(2 * 8 + s) * (NB * NO) + off];
    v4[s] = pA[(size_t)(3 * 8 + s) * (NB * NO) + off];
  }
  float d1 = 0.f, d2 = 0.f, d3 = 0.f, d4 = 0.f;
#pragma unroll
  for (int s = 0; s < 8; ++s) { d1 += v1[s]; d2 += v2[s]; d3 += v3[s]; d4 += v4[s]; }
  const float c1v = d1 + b1[t];
  const float gg = sig_fast(d2);
  const float sh = sinh_fast(d4);
  const float c3v = fmaf(gg, d3 - sh, sh);
  featB[(size_t)b * ND + t] = bf16_rtn(c1v);
  featB[(size_t)b * ND + NO + t] = bf16_rtn(c3v);
  out[off] = fmaf(aS, U[t], fmaf(cS, V[t], b3[t] + Wc[t]));
}

// =============== K3: gemmB 128 blocks (2rh x 8ks x 8ot), 64x64, K=128, atomic out ===============
__global__ __launch_bounds__(512) void k3_gemmB(
    const u16* __restrict__ featB, const float* __restrict__ k3w,
    float* __restrict__ out) {
  __shared__ __align__(16) char smem[32768];
  u16* Ash = (u16*)smem;                 // [64][128] bf16 swizzled, 16 KB
  u16* Bsh = (u16*)(smem + 16384);       // [64 col][128 k], 16 KB
  const int t = threadIdx.x;
  const int lane = t & 63;
  const int wr = (t >> 6) & 3;
  const int wc = t >> 8;
  const int rh = blockIdx.x >> 6, ks = (blockIdx.x >> 3) & 7, ot = blockIdx.x & 7;
  const int r0 = rh * 64, k0 = ks * 128, o0 = ot * 64;

  // ---- batched loads: A (2 x uint4) + B (4 x float4) ----
  uint4 av[2];
#pragma unroll
  for (int p2 = 0; p2 < 2; ++p2) {
    const int s = t + p2 * 512;
    const int row = s >> 4, j8 = (s & 15) * 8;
    av[p2] = *(const uint4*)(featB + (size_t)(r0 + row) * ND + k0 + j8);
  }
  const int gkr = t >> 4, og = t & 15;
  const int go = o0 + og * 4;
  float4 w[4];
#pragma unroll
  for (int kk = 0; kk < 4; ++kk)
    w[kk] = *(const float4*)&k3w[(size_t)(k0 + gkr * 4 + kk) * NO + go];

  // ---- LDS writes ----
#pragma unroll
  for (int p2 = 0; p2 < 2; ++p2) {
    const int s = t + p2 * 512;
    const int row = s >> 4, j8 = (s & 15) * 8;
    const int byte = (row * 256 + j8 * 2) ^ ((row & 7) << 4);
    *(uint4*)((char*)Ash + byte) = av[p2];
  }
  {
    const float* wp0 = (const float*)&w[0];
    const float* wp1 = (const float*)&w[1];
    const float* wp2 = (const float*)&w[2];
    const float* wp3 = (const float*)&w[3];
#pragma unroll
    for (int j = 0; j < 4; ++j) {
      const u16 h0 = bf16_rtn(wp0[j]), h1 = bf16_rtn(wp1[j]);
      const u16 h2 = bf16_rtn(wp2[j]), h3 = bf16_rtn(wp3[j]);
      const int col = og * 4 + j;
      const int byte = (col * 256 + gkr * 8) ^ ((col & 7) << 4);
      *(uint2*)((char*)Bsh + byte) =
          make_uint2((u32)h0 | ((u32)h1 << 16), (u32)h2 | ((u32)h3 << 16));
    }
  }
  __syncthreads();
  // ---- compute ----
  const f32x4 vz = {0.f, 0.f, 0.f, 0.f};
  f32x4 acc[2];
  acc[0] = vz; acc[1] = vz;
#pragma unroll
  for (int ks2 = 0; ks2 < 4; ++ks2) {
    const int kbyte = ks2 * 64 + (lane >> 4) * 16;
    const int row = wr * 16 + (lane & 15);
    const bf16x8 a = *(const bf16x8*)((const char*)Ash + ((row * 256 + kbyte) ^ ((row & 7) << 4)));
#pragma unroll
    for (int n = 0; n < 2; ++n) {
      const int col = wc * 32 + n * 16 + (lane & 15);
      const bf16x8 b = *(const bf16x8*)((const char*)Bsh + ((col * 256 + kbyte) ^ ((col & 7) << 4)));
      acc[n] = __builtin_amdgcn_mfma_f32_16x16x32_bf16(a, b, acc[n], 0, 0, 0);
    }
  }
  // ---- epilogue: atomicAdd into pre-initialized out ----
#pragma unroll
  for (int n = 0; n < 2; ++n) {
    const int col = o0 + wc * 32 + n * 16 + (lane & 15);
#pragma unroll
    for (int r = 0; r < 4; ++r) {
      const int row = r0 + wr * 16 + (lane >> 4) * 4 + r;
      atomicAdd(&out[(size_t)row * NO + col], acc[n][r]);
    }
  }
}

extern "C" void kernel_launch(void* const* d_in, const int* in_sizes, int n_in,
                              void* d_out, int out_size, void* d_ws, size_t ws_size,
                              hipStream_t stream) {
  const float* x    = (const float*)d_in[0];
  const float* gt   = (const float*)d_in[1];
  const float* wt   = (const float*)d_in[2];
  const float* mt   = (const float*)d_in[3];
  const float* k1   = (const float*)d_in[4];
  const float* b1   = (const float*)d_in[5];
  const float* k3   = (const float*)d_in[6];
  const float* b3   = (const float*)d_in[7];
  const float* embk = (const float*)d_in[8];
  const float* embb = (const float*)d_in[9];
  const float* ekd  = (const float*)d_in[10];
  const float* ng   = (const float*)d_in[11];
  const float* nb   = (const float*)d_in[12];

  char* wsb = (char*)d_ws;
  float* Tfull = (float*)wsb;                        // 512 B
  float* U  = (float*)(wsb + 4096);                  // 2 KB each
  float* V  = (float*)(wsb + 8192);
  float* Wc = (float*)(wsb + 12288);
  float* pA = (float*)(wsb + (1u << 20));            // 32*128*512*4 = 8 MB
  u16* featB = (u16*)(wsb + (10u << 20));            // 256 KB
  float* out = (float*)d_out;

  hipLaunchKernelGGL(k1_fused, dim3(392), dim3(512), 0, stream,
                     x, gt, wt, mt, k1, embk, embb, ekd, k3, ng, nb,
                     Tfull, pA, U, V, Wc);
  hipLaunchKernelGGL(k2_combineA, dim3(128), dim3(512), 0, stream,
                     pA, b1, embk, embb, ekd, Tfull, U, V, Wc, b3, featB, out);
  hipLaunchKernelGGL(k3_gemmB, dim3(128), dim3(512), 0, stream,
                     featB, k3, out);
}